// Round 14
// baseline (302.439 us; speedup 1.0000x reference)
//
#include <hip/hip_runtime.h>

// TopK MoE classifier: B=8192, D=4096, E=16, O=512, top-2.
//  k_wr: wr_transpose  W_r [D][E] -> WrT [E][D] f32 (NT reads)
//  k_prep: FUSED router + we_transpose (heterogeneous block ranges):
//      blocks 0..1023: fp32 router, 8 tokens/block (fine-grained so the
//      long-pole router work packs 4/CU and overlaps the transpose blocks)
//      blocks 1024..3071: W_e -> Wbt bf16 transpose, 4 tiles, dbuf prefetch
//      read-once streams (feat, We, Wr) use NON-TEMPORAL loads so
//      featbf/Wbt stay L3-resident for the gemm (R13-verified: gemm FETCH
//      collapsed and it left the top-5)
//  k1b: bucket     16 blocks (1/expert), deterministic ballot compaction
//  k2: moe_gemm    grouped bf16 MFMA 128x256 (8 waves 2Mx4N), BK=32,
//      K-split=2, ring-3 LDS (72 KiB), counted vmcnt(3) + raw s_barrier,
//      XCD-contiguous work mapping; epilogue = plain bf16 stores into
//      g[row] with row = tok (primary expert) or B+tok (secondary) — no
//      prefix/pos indirection
//  k2c: combine    out[t] = w0*(g0[t]+g1[t]+be[e0]) + w1*(g0[B+t]+g1[B+t]
//       +be[e1]); fully streaming reads; block 0 folds balance loss

#define B_ 8192
#define D_ 4096
#define E_ 16
#define O_ 512

typedef unsigned int uint32;
typedef unsigned short ushort_t;
typedef __bf16 bf16_t;
typedef bf16_t bf16x8 __attribute__((ext_vector_type(8)));
typedef float f32x4 __attribute__((ext_vector_type(4)));
typedef ushort_t u16x8 __attribute__((ext_vector_type(8)));

__device__ __forceinline__ uint32 bf16_rne(float x) {
  uint32 u = __float_as_uint(x);
  return (u + 0x7fffu + ((u >> 16) & 1u)) >> 16;
}
__device__ __forceinline__ float bf16_to_f32(ushort_t u) {
  return __uint_as_float(((uint32)u) << 16);
}
__device__ __forceinline__ f32x4 ntload4(const float* p) {
  return __builtin_nontemporal_load((const f32x4*)p);
}

__device__ __forceinline__ void gload16(const void* g, void* l) {
  __builtin_amdgcn_global_load_lds(
      (const __attribute__((address_space(1))) void*)g,
      (__attribute__((address_space(3))) void*)l, 16, 0, 0);
}

// ---------------- kernel wr: W_r transpose ----------------
__global__ __launch_bounds__(256) void wr_transpose(
    const float* __restrict__ Wr, float* __restrict__ WrT) {
  const int d = blockIdx.x * 256 + threadIdx.x;
  const float* src = &Wr[(size_t)d * 16];
  f32x4 v0 = ntload4(src), v1 = ntload4(src + 4);
  f32x4 v2 = ntload4(src + 8), v3 = ntload4(src + 12);
  WrT[0 * D_ + d] = v0[0];  WrT[1 * D_ + d] = v0[1];
  WrT[2 * D_ + d] = v0[2];  WrT[3 * D_ + d] = v0[3];
  WrT[4 * D_ + d] = v1[0];  WrT[5 * D_ + d] = v1[1];
  WrT[6 * D_ + d] = v1[2];  WrT[7 * D_ + d] = v1[3];
  WrT[8 * D_ + d] = v2[0];  WrT[9 * D_ + d] = v2[1];
  WrT[10 * D_ + d] = v2[2]; WrT[11 * D_ + d] = v2[3];
  WrT[12 * D_ + d] = v3[0]; WrT[13 * D_ + d] = v3[1];
  WrT[14 * D_ + d] = v3[2]; WrT[15 * D_ + d] = v3[3];
}

// ---------------- fused prep: router (blocks 0..1023) + We transpose ------
__global__ __launch_bounds__(256) void prep(
    const float* __restrict__ feat, const float* __restrict__ WrT,
    const float* __restrict__ br, const float* __restrict__ We,
    ushort_t* __restrict__ featbf, ushort_t* __restrict__ Wbt,
    int* __restrict__ idxP, float2* __restrict__ wP,
    float* __restrict__ pblk) {
  __shared__ __align__(16) float shmem[64 * 65];  // union: router pw / we tile
  const int tid = threadIdx.x;

  if (blockIdx.x < 1024) {
    // ---------------- router part: 8 tokens (2 per wave) ----------------
    const int lane = tid & 63, w = tid >> 6;
    const int tbase = blockIdx.x * 8 + w * 2;

    float acc[2][16] = {};

    for (int si = 0; si < 8; ++si) {
      const int d8 = si * 512 + lane * 8;
      f32x4 fa[2], fb[2];
#pragma unroll
      for (int i = 0; i < 2; ++i) {
        const float* fp = &feat[(size_t)(tbase + i) * D_ + d8];
        fa[i] = ntload4(fp);
        fb[i] = ntload4(fp + 4);
      }
#pragma unroll
      for (int i = 0; i < 2; ++i) {
        uint4 pk;
        pk.x = bf16_rne(fa[i][0]) | (bf16_rne(fa[i][1]) << 16);
        pk.y = bf16_rne(fa[i][2]) | (bf16_rne(fa[i][3]) << 16);
        pk.z = bf16_rne(fb[i][0]) | (bf16_rne(fb[i][1]) << 16);
        pk.w = bf16_rne(fb[i][2]) | (bf16_rne(fb[i][3]) << 16);
        *(uint4*)&featbf[(size_t)(tbase + i) * D_ + d8] = pk;
      }
#pragma unroll
      for (int e = 0; e < 16; ++e) {
        const float* wp = &WrT[(size_t)e * D_ + d8];
        f32x4 wa = *(const f32x4*)wp;       // WrT reused -> keep cached
        f32x4 wb = *(const f32x4*)(wp + 4);
#pragma unroll
        for (int i = 0; i < 2; ++i) {
          float a = acc[i][e];
          a = fmaf(fa[i][0], wa[0], a);
          a = fmaf(fa[i][1], wa[1], a);
          a = fmaf(fa[i][2], wa[2], a);
          a = fmaf(fa[i][3], wa[3], a);
          a = fmaf(fb[i][0], wb[0], a);
          a = fmaf(fb[i][1], wb[1], a);
          a = fmaf(fb[i][2], wb[2], a);
          a = fmaf(fb[i][3], wb[3], a);
          acc[i][e] = a;
        }
      }
    }

    float psum[16];
#pragma unroll
    for (int e = 0; e < 16; ++e) psum[e] = 0.f;

#pragma unroll
    for (int i = 0; i < 2; ++i) {
      float l[16];
#pragma unroll
      for (int e = 0; e < 16; ++e) {
        float v = acc[i][e];
#pragma unroll
        for (int m = 32; m >= 1; m >>= 1) v += __shfl_xor(v, m, 64);
        l[e] = v + br[e];
      }
      float mx = l[0];
#pragma unroll
      for (int e = 1; e < 16; ++e) mx = fmaxf(mx, l[e]);
      float p[16];
      float s = 0.f;
#pragma unroll
      for (int e = 0; e < 16; ++e) { p[e] = expf(l[e] - mx); s += p[e]; }
      float inv = 1.f / s;
#pragma unroll
      for (int e = 0; e < 16; ++e) { p[e] *= inv; psum[e] += p[e]; }
      int i0 = 0; float v0 = p[0];
#pragma unroll
      for (int e = 1; e < 16; ++e) if (p[e] > v0) { v0 = p[e]; i0 = e; }
      int i1 = (i0 == 0) ? 1 : 0; float v1 = p[i1];
#pragma unroll
      for (int e = 0; e < 16; ++e)
        if (e != i0 && p[e] > v1) { v1 = p[e]; i1 = e; }
      float denom = fmaxf(v0 + v1, 1e-9f);
      if (lane == 0) {
        int t = tbase + i;
        idxP[t] = i0 | (i1 << 8);
        wP[t] = make_float2(v0 / denom, v1 / denom);
      }
    }
    if (lane == 0) {
#pragma unroll
      for (int e = 0; e < 16; ++e) shmem[w * 16 + e] = psum[e];
    }
    __syncthreads();
    if (tid < 16)
      pblk[blockIdx.x * 16 + tid] =
          (shmem[tid] + shmem[16 + tid]) + (shmem[32 + tid] + shmem[48 + tid]);
  } else {
    // ------- We transpose part: 4 tiles of 64x64, dbuf register prefetch --
    const int tx = tid & 15, ty = tid >> 4;
    const int wid = blockIdx.x - 1024;  // 0..2047
    f32x4 cur[4], nxt[4];
    {
      const int tix = wid * 4;
      const int e = tix >> 9;
      const int rem = tix & 511;
      const int d0 = (rem >> 3) << 6, o0 = (rem & 7) << 6;
      const float* src = We + ((size_t)e * D_ + d0) * O_ + o0;
#pragma unroll
      for (int p = 0; p < 4; ++p)
        cur[p] = ntload4(src + (size_t)(ty + p * 16) * O_ + tx * 4);
    }
#pragma unroll
    for (int q = 0; q < 4; ++q) {
      const int tix = wid * 4 + q;
      const int e = tix >> 9;
      const int rem = tix & 511;
      const int d0 = (rem >> 3) << 6, o0 = (rem & 7) << 6;
      if (q) __syncthreads();
#pragma unroll
      for (int p = 0; p < 4; ++p) {
        int dl = ty + p * 16;
        shmem[dl * 65 + tx * 4 + 0] = cur[p][0];
        shmem[dl * 65 + tx * 4 + 1] = cur[p][1];
        shmem[dl * 65 + tx * 4 + 2] = cur[p][2];
        shmem[dl * 65 + tx * 4 + 3] = cur[p][3];
      }
      if (q < 3) {
        const int tix2 = tix + 1;
        const int e2 = tix2 >> 9;
        const int rem2 = tix2 & 511;
        const int d02 = (rem2 >> 3) << 6, o02 = (rem2 & 7) << 6;
        const float* src2 = We + ((size_t)e2 * D_ + d02) * O_ + o02;
#pragma unroll
        for (int p = 0; p < 4; ++p)
          nxt[p] = ntload4(src2 + (size_t)(ty + p * 16) * O_ + tx * 4);
      }
      __syncthreads();
      ushort_t* dst = Wbt + ((size_t)e * O_ + o0) * D_ + d0;
#pragma unroll
      for (int p = 0; p < 4; ++p) {
        int ol = ty + p * 16;
        uint2 pk;
        pk.x = bf16_rne(shmem[(tx * 4 + 0) * 65 + ol]) |
               (bf16_rne(shmem[(tx * 4 + 1) * 65 + ol]) << 16);
        pk.y = bf16_rne(shmem[(tx * 4 + 2) * 65 + ol]) |
               (bf16_rne(shmem[(tx * 4 + 3) * 65 + ol]) << 16);
        *(uint2*)(dst + (size_t)ol * D_ + tx * 4) = pk;
      }
#pragma unroll
      for (int p = 0; p < 4; ++p) cur[p] = nxt[p];
    }
  }
}

// ---------------- kernel 1b: deterministic expert bucketing ----------------
__global__ __launch_bounds__(256) void bucket(
    const int* __restrict__ idxP, const float2* __restrict__ wP,
    int* __restrict__ tokL, float* __restrict__ wgtL, int* __restrict__ cntA) {
  const int e = blockIdx.x;
  const int tid = threadIdx.x, lane = tid & 63, w = tid >> 6;
  __shared__ int wsum[4];
  __shared__ int basev;
  if (tid == 0) basev = 0;
  __syncthreads();

  for (int c = 0; c < B_; c += 256) {
    const int t = c + tid;
    const int pk = idxP[t];
    const float2 wv = wP[t];
    const bool m0 = (pk & 255) == e;
    const bool m1 = (pk >> 8) == e;
    const bool m = m0 || m1;
    const float wt = m0 ? wv.x : wv.y;
    unsigned long long bal = __ballot(m);
    int rank = __popcll(bal & ((1ull << lane) - 1ull));
    if (lane == 0) wsum[w] = __popcll(bal);
    __syncthreads();
    int wbase = basev;
    for (int q = 0; q < w; ++q) wbase += wsum[q];
    if (m) {
      int pos = wbase + rank;
      tokL[e * B_ + pos] = t;
      wgtL[e * B_ + pos] = wt;
    }
    __syncthreads();
    if (tid == 0) basev += (wsum[0] + wsum[1]) + (wsum[2] + wsum[3]);
  }
  __syncthreads();
  if (tid == 0) cntA[e] = basev;
}

// ---------------- kernel 2: grouped expert GEMM, 128x256, K-split=2 -------
// 8 waves (2Mx4N), BK=32, ring-3 LDS (72 KiB), counted vmcnt(3) + raw
// s_barrier. XCD-contiguous mapping. Epilogue: g row = tok (primary) or
// B+tok (secondary) — token-indexed, no prefix.
#define VM3 asm volatile("s_waitcnt vmcnt(3)" ::: "memory")
#define VM0 asm volatile("s_waitcnt vmcnt(0)" ::: "memory")

__global__ __launch_bounds__(512, 4) void moe_gemm(
    const ushort_t* __restrict__ featbf, const ushort_t* __restrict__ Wbt,
    const float* __restrict__ be, const int* __restrict__ tokL,
    const float* __restrict__ wgtL, const int* __restrict__ cntA,
    const int* __restrict__ idxP, ushort_t* __restrict__ g0,
    ushort_t* __restrict__ g1, float* __restrict__ out, int dense) {
  const int orig = blockIdx.x;                  // 0..4095
  const int work = (orig & 7) * 512 + (orig >> 3);
  const int z = work >> 7;                      // e*2 + khalf
  const int e = z >> 1, khalf = z & 1;
  const int cnt = cntA[e];
  const int row0 = ((work >> 1) & 63) * 128;
  if (row0 >= cnt) return;
  const int o0 = (work & 1) * 256;

  const int tid = threadIdx.x;
  const int lane = tid & 63, w = tid >> 6;      // w in [0,8)
  const int wm = w >> 2, wn = w & 3;            // 2M x 4N

  __shared__ __align__(16) ushort_t As[3][128 * 32];
  __shared__ __align__(16) ushort_t Bs[3][256 * 32];

  const int kg = (lane & 3) ^ ((lane >> 3) & 3);
  const size_t kbase = (size_t)khalf * 2048 + kg * 8;
  const int arow = row0 + w * 16 + (lane >> 2);
  const int atok = (arow < cnt) ? tokL[e * B_ + arow] : 0;
  const ushort_t* aS = featbf + (size_t)atok * D_ + kbase;
  const ushort_t* bS[2];
#pragma unroll
  for (int j = 0; j < 2; ++j) {
    int r = (2 * w + j) * 16 + (lane >> 2);
    bS[j] = Wbt + ((size_t)e * O_ + o0 + r) * D_ + kbase;
  }

  f32x4 acc[4][4] = {};
  const int lr = lane & 15;
  const int lg = lane >> 4;
  const int ps = (lg ^ ((lr >> 1) & 3)) * 8;

#define STAGE(buf, t)                                                \
  {                                                                  \
    gload16(aS + (t) * 32, &As[buf][(w * 16) * 32]);                 \
    gload16(bS[0] + (t) * 32, &Bs[buf][(2 * w) * 512]);              \
    gload16(bS[1] + (t) * 32, &Bs[buf][(2 * w + 1) * 512]);          \
  }

#define COMPUTE(buf)                                                 \
  {                                                                  \
    bf16x8 af[4], bf[4];                                             \
    _Pragma("unroll") for (int m = 0; m < 4; ++m)                    \
        af[m] = *(const bf16x8*)&As[buf][(wm * 64 + m * 16 + lr) * 32 + ps]; \
    _Pragma("unroll") for (int n = 0; n < 4; ++n)                    \
        bf[n] = *(const bf16x8*)&Bs[buf][(wn * 64 + n * 16 + lr) * 32 + ps]; \
    __builtin_amdgcn_s_setprio(1);                                   \
    _Pragma("unroll") for (int m = 0; m < 4; ++m)                    \
        _Pragma("unroll") for (int n = 0; n < 4; ++n)                \
            acc[m][n] = __builtin_amdgcn_mfma_f32_16x16x32_bf16(     \
                af[m], bf[n], acc[m][n], 0, 0, 0);                   \
    __builtin_amdgcn_s_setprio(0);                                   \
  }

  STAGE(0, 0);
  STAGE(1, 1);
  for (int tt = 0; tt < 20; ++tt) {  // t = 0..59
    const int t = tt * 3;
    VM3; __builtin_amdgcn_s_barrier(); COMPUTE(0); STAGE(2, t + 2);
    VM3; __builtin_amdgcn_s_barrier(); COMPUTE(1); STAGE(0, t + 3);
    VM3; __builtin_amdgcn_s_barrier(); COMPUTE(2); STAGE(1, t + 4);
  }
  VM3; __builtin_amdgcn_s_barrier(); COMPUTE(0); STAGE(2, 62);  // t=60
  VM3; __builtin_amdgcn_s_barrier(); COMPUTE(1); STAGE(0, 63);  // t=61
  VM3; __builtin_amdgcn_s_barrier(); COMPUTE(2);                // t=62
  VM0; __builtin_amdgcn_s_barrier(); COMPUTE(0);                // t=63

  if (dense) {
    ushort_t* G = khalf ? g1 : g0;
#pragma unroll
    for (int m = 0; m < 4; ++m) {
#pragma unroll
      for (int i = 0; i < 4; ++i) {
        int gr = row0 + wm * 64 + m * 16 + (lane >> 4) * 4 + i;
        if (gr < cnt) {
          int tk = tokL[e * B_ + gr];
          size_t row = ((idxP[tk] & 255) == e) ? (size_t)tk : (size_t)(B_ + tk);
#pragma unroll
          for (int n = 0; n < 4; ++n) {
            int o = o0 + wn * 64 + n * 16 + (lane & 15);
            G[row * O_ + o] = (ushort_t)bf16_rne(acc[m][n][i]);
          }
        }
      }
    }
  } else {
#pragma unroll
    for (int m = 0; m < 4; ++m) {
#pragma unroll
      for (int i = 0; i < 4; ++i) {
        int gr = row0 + wm * 64 + m * 16 + (lane >> 4) * 4 + i;
        if (gr < cnt) {
          int tk = tokL[e * B_ + gr];
          float wt = wgtL[e * B_ + gr];
#pragma unroll
          for (int n = 0; n < 4; ++n) {
            int o = o0 + wn * 64 + n * 16 + (lane & 15);
            float v = acc[m][n][i] + (khalf ? 0.f : be[e * O_ + o]);
            atomicAdd(&out[(size_t)tk * O_ + o], wt * v);
          }
        }
      }
    }
  }
#undef STAGE
#undef COMPUTE
}

// ---------------- kernel 2c: combine + fused balance loss ----------------
// Streaming: out[t] = w0*(g0[t]+g1[t]+be[e0]) + w1*(g0[B+t]+g1[B+t]+be[e1])
__global__ __launch_bounds__(256) void combine(
    const ushort_t* __restrict__ g0, const ushort_t* __restrict__ g1,
    const int* __restrict__ idxP, const float2* __restrict__ wP,
    const float* __restrict__ be, const float* __restrict__ pblk,
    float* __restrict__ out) {
  const int tid = threadIdx.x;
  const int t = blockIdx.x * 4 + (tid >> 6);
  const int o = (tid & 63) * 8;
  const int pk = idxP[t];
  const int e0 = pk & 255, e1 = pk >> 8;
  const float2 wv = wP[t];
  const size_t s0 = (size_t)t * O_ + o;
  const size_t s1 = (size_t)(B_ + t) * O_ + o;
  u16x8 a0 = *(const u16x8*)&g0[s0];
  u16x8 a1 = *(const u16x8*)&g1[s0];
  u16x8 b0 = *(const u16x8*)&g0[s1];
  u16x8 b1 = *(const u16x8*)&g1[s1];
  const float* be0 = &be[e0 * O_ + o];
  const float* be1 = &be[e1 * O_ + o];
  float r[8];
#pragma unroll
  for (int j = 0; j < 8; ++j) {
    float a = bf16_to_f32(a0[j]) + bf16_to_f32(a1[j]) + be0[j];
    float b = bf16_to_f32(b0[j]) + bf16_to_f32(b1[j]) + be1[j];
    r[j] = wv.x * a + wv.y * b;
  }
  *(f32x4*)&out[(size_t)t * O_ + o] = f32x4{r[0], r[1], r[2], r[3]};
  *(f32x4*)&out[(size_t)t * O_ + o + 4] = f32x4{r[4], r[5], r[6], r[7]};

  if (blockIdx.x == 0) {
    __shared__ float red[64];
    if (tid < 64) {
      const int e = tid & 15, g = tid >> 4;
      float acc = 0.f;
      for (int b = g; b < 1024; b += 4) acc += pblk[b * 16 + e];
      red[tid] = acc;
    }
    __syncthreads();
    if (tid < 16) {
      float tot = (red[tid] + red[16 + tid]) + (red[32 + tid] + red[48 + tid]);
      float pi = tot * (1.f / (float)B_);
      red[tid] = pi * logf(fmaxf(pi, 1e-9f));
    }
    __syncthreads();
    if (tid == 0) {
      float loss = 0.f;
#pragma unroll
      for (int e2 = 0; e2 < 16; ++e2) loss += red[e2];
      out[(size_t)B_ * O_] = 0.01f * (loss + logf(16.f));
    }
  }
}

// ---------------- kernel 3: balance loss (fallback path only) ------------
__global__ __launch_bounds__(64) void finalize(const float* __restrict__ pblk,
                                               float* __restrict__ out) {
  __shared__ float red[64];
  const int tid = threadIdx.x;
  const int e = tid & 15, g = tid >> 4;
  float s = 0.f;
  for (int b = g; b < 1024; b += 4) s += pblk[b * 16 + e];
  red[tid] = s;
  __syncthreads();
  if (tid < 16) {
    float tot = (red[tid] + red[16 + tid]) + (red[32 + tid] + red[48 + tid]);
    float pi = tot * (1.f / (float)B_);
    red[tid] = pi * logf(fmaxf(pi, 1e-9f));
  }
  __syncthreads();
  if (tid == 0) {
    float loss = 0.f;
#pragma unroll
    for (int e2 = 0; e2 < 16; ++e2) loss += red[e2];
    out[(size_t)B_ * O_] = 0.01f * (loss + logf(16.f));
  }
}

extern "C" void kernel_launch(void* const* d_in, const int* in_sizes, int n_in,
                              void* d_out, int out_size, void* d_ws,
                              size_t ws_size, hipStream_t stream) {
  const float* feat = (const float*)d_in[0];
  const float* Wr = (const float*)d_in[1];
  const float* br = (const float*)d_in[2];
  const float* We = (const float*)d_in[3];
  const float* be = (const float*)d_in[4];
  float* out = (float*)d_out;

  char* ws = (char*)d_ws;
  const size_t SZG     = (size_t)(2 * B_) * O_ * 2;   // 16 MiB per half (bf16)
  const size_t OFF_FEAT = 67108864;                   // 64 MiB Wbt
  const size_t OFF_G0   = OFF_FEAT + 67108864;        // 64 MiB featbf
  const size_t OFF_G1   = OFF_G0 + SZG;
  const size_t OFF_TOK  = OFF_G1 + SZG;
  const size_t OFF_WGT  = OFF_TOK + 524288;
  const size_t OFF_CNT  = OFF_WGT + 524288;
  const size_t OFF_IDX  = OFF_CNT + 256;
  const size_t OFF_WP   = OFF_IDX + 32768;
  const size_t OFF_PB   = OFF_WP + 65536;             // pblk: 1024*16 f32
  const size_t OFF_WRT  = OFF_PB + 65536;             // WrT: 256 KB
  const size_t NEED     = OFF_WRT + 262144;
  ushort_t* Wbt = (ushort_t*)ws;
  ushort_t* featbf = (ushort_t*)(ws + OFF_FEAT);
  ushort_t* g0 = (ushort_t*)(ws + OFF_G0);
  ushort_t* g1 = (ushort_t*)(ws + OFF_G1);
  int* tokL = (int*)(ws + OFF_TOK);
  float* wgtL = (float*)(ws + OFF_WGT);
  int* cntA = (int*)(ws + OFF_CNT);
  int* idxP = (int*)(ws + OFF_IDX);
  float2* wP = (float2*)(ws + OFF_WP);
  float* pblk = (float*)(ws + OFF_PB);
  float* WrT = (float*)(ws + OFF_WRT);
  const int dense = ws_size >= NEED ? 1 : 0;

  if (!dense)
    hipMemsetAsync(out, 0, (size_t)(B_ * O_ + 1) * sizeof(float), stream);

  wr_transpose<<<D_ / 256, 256, 0, stream>>>(Wr, WrT);
  prep<<<1024 + 2048, 256, 0, stream>>>(feat, WrT, br, We, featbf, Wbt, idxP,
                                        wP, pblk);
  bucket<<<E_, 256, 0, stream>>>(idxP, wP, tokL, wgtL, cntA);
  moe_gemm<<<4096, 512, 0, stream>>>(featbf, Wbt, be, tokL, wgtL, cntA, idxP,
                                     g0, g1, out, dense);
  if (dense)
    combine<<<B_ / 4, 256, 0, stream>>>(g0, g1, idxP, wP, be, pblk, out);
  else
    finalize<<<1, 64, 0, stream>>>(pblk, out);
}

// Round 15
// 258.327 us; speedup vs baseline: 1.1708x; 1.1708x over previous
//
#include <hip/hip_runtime.h>

// TopK MoE classifier: B=8192, D=4096, E=16, O=512, top-2.
//  k_wr: wr_transpose  W_r [D][E] -> WrT [E][D] f32 (NT reads)
//  k_prep: FUSED router_mlp + we_transpose (heterogeneous block ranges):
//      blocks 0..511: fp32 router logits/top-2 + feat f32->bf16 (featbf),
//      16 tokens/block (4/wave) — best measured balance (R13: 103 us; the
//      R14 1024x8 split regressed via 2x WrT re-reads)
//      blocks 512..2559: W_e -> Wbt bf16 transpose, 4 tiles, dbuf prefetch
//      read-once streams (feat, We, Wr) use NON-TEMPORAL loads
//  k1b: bucket     16 blocks (1/expert), deterministic ballot compaction;
//       records posA/posB = token's slot inside its expert lists
//  k2: moe_gemm    grouped bf16 MFMA 128x256 (8 waves 2Mx4N), BK=32,
//      K-split=2, ring-3 LDS (72 KiB), counted vmcnt(3) + raw s_barrier,
//      XCD-contiguous work mapping; epilogue = plain CONTIGUOUS bf16
//      stores into g[cntOff[e]+row] (R14's token-indexed scatter regressed)
//  k2c: combine    out[t] = w0*(g0+g1+be[e0]) + w1*(g0+g1+be[e1]);
//       block 0 folds the balance-loss finalize

#define B_ 8192
#define D_ 4096
#define E_ 16
#define O_ 512

typedef unsigned int uint32;
typedef unsigned short ushort_t;
typedef __bf16 bf16_t;
typedef bf16_t bf16x8 __attribute__((ext_vector_type(8)));
typedef float f32x4 __attribute__((ext_vector_type(4)));
typedef ushort_t u16x8 __attribute__((ext_vector_type(8)));

__device__ __forceinline__ uint32 bf16_rne(float x) {
  uint32 u = __float_as_uint(x);
  return (u + 0x7fffu + ((u >> 16) & 1u)) >> 16;
}
__device__ __forceinline__ float bf16_to_f32(ushort_t u) {
  return __uint_as_float(((uint32)u) << 16);
}
__device__ __forceinline__ f32x4 ntload4(const float* p) {
  return __builtin_nontemporal_load((const f32x4*)p);
}

__device__ __forceinline__ void gload16(const void* g, void* l) {
  __builtin_amdgcn_global_load_lds(
      (const __attribute__((address_space(1))) void*)g,
      (__attribute__((address_space(3))) void*)l, 16, 0, 0);
}

// ---------------- kernel wr: W_r transpose ----------------
__global__ __launch_bounds__(256) void wr_transpose(
    const float* __restrict__ Wr, float* __restrict__ WrT) {
  const int d = blockIdx.x * 256 + threadIdx.x;
  const float* src = &Wr[(size_t)d * 16];
  f32x4 v0 = ntload4(src), v1 = ntload4(src + 4);
  f32x4 v2 = ntload4(src + 8), v3 = ntload4(src + 12);
  WrT[0 * D_ + d] = v0[0];  WrT[1 * D_ + d] = v0[1];
  WrT[2 * D_ + d] = v0[2];  WrT[3 * D_ + d] = v0[3];
  WrT[4 * D_ + d] = v1[0];  WrT[5 * D_ + d] = v1[1];
  WrT[6 * D_ + d] = v1[2];  WrT[7 * D_ + d] = v1[3];
  WrT[8 * D_ + d] = v2[0];  WrT[9 * D_ + d] = v2[1];
  WrT[10 * D_ + d] = v2[2]; WrT[11 * D_ + d] = v2[3];
  WrT[12 * D_ + d] = v3[0]; WrT[13 * D_ + d] = v3[1];
  WrT[14 * D_ + d] = v3[2]; WrT[15 * D_ + d] = v3[3];
}

// ---------------- fused prep: router (blocks 0..511) + We transpose -------
__global__ __launch_bounds__(256) void prep(
    const float* __restrict__ feat, const float* __restrict__ WrT,
    const float* __restrict__ br, const float* __restrict__ We,
    ushort_t* __restrict__ featbf, ushort_t* __restrict__ Wbt,
    int* __restrict__ idxP, float2* __restrict__ wP,
    float* __restrict__ pblk) {
  __shared__ __align__(16) float shmem[64 * 65];  // union: router pw / we tile
  const int tid = threadIdx.x;

  if (blockIdx.x < 512) {
    // ---------------- router part ----------------
    const int lane = tid & 63, w = tid >> 6;
    const int tbase = blockIdx.x * 16 + w * 4;

    float acc[4][16] = {};

    for (int si = 0; si < 8; ++si) {
      const int d8 = si * 512 + lane * 8;
      f32x4 fa[4], fb[4];
#pragma unroll
      for (int i = 0; i < 4; ++i) {
        const float* fp = &feat[(size_t)(tbase + i) * D_ + d8];
        fa[i] = ntload4(fp);
        fb[i] = ntload4(fp + 4);
      }
#pragma unroll
      for (int i = 0; i < 4; ++i) {
        uint4 pk;
        pk.x = bf16_rne(fa[i][0]) | (bf16_rne(fa[i][1]) << 16);
        pk.y = bf16_rne(fa[i][2]) | (bf16_rne(fa[i][3]) << 16);
        pk.z = bf16_rne(fb[i][0]) | (bf16_rne(fb[i][1]) << 16);
        pk.w = bf16_rne(fb[i][2]) | (bf16_rne(fb[i][3]) << 16);
        *(uint4*)&featbf[(size_t)(tbase + i) * D_ + d8] = pk;
      }
#pragma unroll
      for (int e = 0; e < 16; ++e) {
        const float* wp = &WrT[(size_t)e * D_ + d8];
        f32x4 wa = *(const f32x4*)wp;       // WrT reused -> keep cached
        f32x4 wb = *(const f32x4*)(wp + 4);
#pragma unroll
        for (int i = 0; i < 4; ++i) {
          float a = acc[i][e];
          a = fmaf(fa[i][0], wa[0], a);
          a = fmaf(fa[i][1], wa[1], a);
          a = fmaf(fa[i][2], wa[2], a);
          a = fmaf(fa[i][3], wa[3], a);
          a = fmaf(fb[i][0], wb[0], a);
          a = fmaf(fb[i][1], wb[1], a);
          a = fmaf(fb[i][2], wb[2], a);
          a = fmaf(fb[i][3], wb[3], a);
          acc[i][e] = a;
        }
      }
    }

    float psum[16];
#pragma unroll
    for (int e = 0; e < 16; ++e) psum[e] = 0.f;

#pragma unroll
    for (int i = 0; i < 4; ++i) {
      float l[16];
#pragma unroll
      for (int e = 0; e < 16; ++e) {
        float v = acc[i][e];
#pragma unroll
        for (int m = 32; m >= 1; m >>= 1) v += __shfl_xor(v, m, 64);
        l[e] = v + br[e];
      }
      float mx = l[0];
#pragma unroll
      for (int e = 1; e < 16; ++e) mx = fmaxf(mx, l[e]);
      float p[16];
      float s = 0.f;
#pragma unroll
      for (int e = 0; e < 16; ++e) { p[e] = expf(l[e] - mx); s += p[e]; }
      float inv = 1.f / s;
#pragma unroll
      for (int e = 0; e < 16; ++e) { p[e] *= inv; psum[e] += p[e]; }
      int i0 = 0; float v0 = p[0];
#pragma unroll
      for (int e = 1; e < 16; ++e) if (p[e] > v0) { v0 = p[e]; i0 = e; }
      int i1 = (i0 == 0) ? 1 : 0; float v1 = p[i1];
#pragma unroll
      for (int e = 0; e < 16; ++e)
        if (e != i0 && p[e] > v1) { v1 = p[e]; i1 = e; }
      float denom = fmaxf(v0 + v1, 1e-9f);
      if (lane == 0) {
        int t = tbase + i;
        idxP[t] = i0 | (i1 << 8);
        wP[t] = make_float2(v0 / denom, v1 / denom);
      }
    }
    if (lane == 0) {
#pragma unroll
      for (int e = 0; e < 16; ++e) shmem[w * 16 + e] = psum[e];
    }
    __syncthreads();
    if (tid < 16)
      pblk[blockIdx.x * 16 + tid] =
          (shmem[tid] + shmem[16 + tid]) + (shmem[32 + tid] + shmem[48 + tid]);
  } else {
    // ------- We transpose part: 4 tiles of 64x64, dbuf register prefetch --
    const int tx = tid & 15, ty = tid >> 4;
    const int wid = blockIdx.x - 512;  // 0..2047
    f32x4 cur[4], nxt[4];
    {
      const int tix = wid * 4;
      const int e = tix >> 9;
      const int rem = tix & 511;
      const int d0 = (rem >> 3) << 6, o0 = (rem & 7) << 6;
      const float* src = We + ((size_t)e * D_ + d0) * O_ + o0;
#pragma unroll
      for (int p = 0; p < 4; ++p)
        cur[p] = ntload4(src + (size_t)(ty + p * 16) * O_ + tx * 4);
    }
#pragma unroll
    for (int q = 0; q < 4; ++q) {
      const int tix = wid * 4 + q;
      const int e = tix >> 9;
      const int rem = tix & 511;
      const int d0 = (rem >> 3) << 6, o0 = (rem & 7) << 6;
      if (q) __syncthreads();
#pragma unroll
      for (int p = 0; p < 4; ++p) {
        int dl = ty + p * 16;
        shmem[dl * 65 + tx * 4 + 0] = cur[p][0];
        shmem[dl * 65 + tx * 4 + 1] = cur[p][1];
        shmem[dl * 65 + tx * 4 + 2] = cur[p][2];
        shmem[dl * 65 + tx * 4 + 3] = cur[p][3];
      }
      if (q < 3) {
        const int tix2 = tix + 1;
        const int e2 = tix2 >> 9;
        const int rem2 = tix2 & 511;
        const int d02 = (rem2 >> 3) << 6, o02 = (rem2 & 7) << 6;
        const float* src2 = We + ((size_t)e2 * D_ + d02) * O_ + o02;
#pragma unroll
        for (int p = 0; p < 4; ++p)
          nxt[p] = ntload4(src2 + (size_t)(ty + p * 16) * O_ + tx * 4);
      }
      __syncthreads();
      ushort_t* dst = Wbt + ((size_t)e * O_ + o0) * D_ + d0;
#pragma unroll
      for (int p = 0; p < 4; ++p) {
        int ol = ty + p * 16;
        uint2 pk;
        pk.x = bf16_rne(shmem[(tx * 4 + 0) * 65 + ol]) |
               (bf16_rne(shmem[(tx * 4 + 1) * 65 + ol]) << 16);
        pk.y = bf16_rne(shmem[(tx * 4 + 2) * 65 + ol]) |
               (bf16_rne(shmem[(tx * 4 + 3) * 65 + ol]) << 16);
        *(uint2*)(dst + (size_t)ol * D_ + tx * 4) = pk;
      }
#pragma unroll
      for (int p = 0; p < 4; ++p) cur[p] = nxt[p];
    }
  }
}

// ---------------- kernel 1b: deterministic expert bucketing ----------------
__global__ __launch_bounds__(256) void bucket(
    const int* __restrict__ idxP, const float2* __restrict__ wP,
    int* __restrict__ tokL, float* __restrict__ wgtL, int* __restrict__ cntA,
    int* __restrict__ posA, int* __restrict__ posB) {
  const int e = blockIdx.x;
  const int tid = threadIdx.x, lane = tid & 63, w = tid >> 6;
  __shared__ int wsum[4];
  __shared__ int basev;
  if (tid == 0) basev = 0;
  __syncthreads();

  for (int c = 0; c < B_; c += 256) {
    const int t = c + tid;
    const int pk = idxP[t];
    const float2 wv = wP[t];
    const bool m0 = (pk & 255) == e;
    const bool m1 = (pk >> 8) == e;
    const bool m = m0 || m1;
    const float wt = m0 ? wv.x : wv.y;
    unsigned long long bal = __ballot(m);
    int rank = __popcll(bal & ((1ull << lane) - 1ull));
    if (lane == 0) wsum[w] = __popcll(bal);
    __syncthreads();
    int wbase = basev;
    for (int q = 0; q < w; ++q) wbase += wsum[q];
    if (m) {
      int pos = wbase + rank;
      tokL[e * B_ + pos] = t;
      wgtL[e * B_ + pos] = wt;
      if (m0) posA[t] = pos; else posB[t] = pos;
    }
    __syncthreads();
    if (tid == 0) basev += (wsum[0] + wsum[1]) + (wsum[2] + wsum[3]);
  }
  __syncthreads();
  if (tid == 0) cntA[e] = basev;
}

// ---------------- kernel 2: grouped expert GEMM, 128x256, K-split=2 -------
// 8 waves (2Mx4N), BK=32, ring-3 LDS (72 KiB), counted vmcnt(3) + raw
// s_barrier (STAGE after COMPUTE). XCD-contiguous mapping. bf16 g epilogue,
// contiguous (cntOff[e]+row)-indexed stores.
#define VM3 asm volatile("s_waitcnt vmcnt(3)" ::: "memory")
#define VM0 asm volatile("s_waitcnt vmcnt(0)" ::: "memory")

__global__ __launch_bounds__(512, 4) void moe_gemm(
    const ushort_t* __restrict__ featbf, const ushort_t* __restrict__ Wbt,
    const float* __restrict__ be, const int* __restrict__ tokL,
    const float* __restrict__ wgtL, const int* __restrict__ cntA,
    ushort_t* __restrict__ g0, ushort_t* __restrict__ g1,
    float* __restrict__ out, int dense) {
  const int orig = blockIdx.x;                  // 0..4095
  const int work = (orig & 7) * 512 + (orig >> 3);
  const int z = work >> 7;                      // e*2 + khalf
  const int e = z >> 1, khalf = z & 1;
  const int cnt = cntA[e];
  const int row0 = ((work >> 1) & 63) * 128;
  if (row0 >= cnt) return;
  const int o0 = (work & 1) * 256;

  const int tid = threadIdx.x;
  const int lane = tid & 63, w = tid >> 6;      // w in [0,8)
  const int wm = w >> 2, wn = w & 3;            // 2M x 4N

  __shared__ __align__(16) ushort_t As[3][128 * 32];
  __shared__ __align__(16) ushort_t Bs[3][256 * 32];

  const int kg = (lane & 3) ^ ((lane >> 3) & 3);
  const size_t kbase = (size_t)khalf * 2048 + kg * 8;
  const int arow = row0 + w * 16 + (lane >> 2);
  const int atok = (arow < cnt) ? tokL[e * B_ + arow] : 0;
  const ushort_t* aS = featbf + (size_t)atok * D_ + kbase;
  const ushort_t* bS[2];
#pragma unroll
  for (int j = 0; j < 2; ++j) {
    int r = (2 * w + j) * 16 + (lane >> 2);
    bS[j] = Wbt + ((size_t)e * O_ + o0 + r) * D_ + kbase;
  }

  f32x4 acc[4][4] = {};
  const int lr = lane & 15;
  const int lg = lane >> 4;
  const int ps = (lg ^ ((lr >> 1) & 3)) * 8;

#define STAGE(buf, t)                                                \
  {                                                                  \
    gload16(aS + (t) * 32, &As[buf][(w * 16) * 32]);                 \
    gload16(bS[0] + (t) * 32, &Bs[buf][(2 * w) * 512]);              \
    gload16(bS[1] + (t) * 32, &Bs[buf][(2 * w + 1) * 512]);          \
  }

#define COMPUTE(buf)                                                 \
  {                                                                  \
    bf16x8 af[4], bf[4];                                             \
    _Pragma("unroll") for (int m = 0; m < 4; ++m)                    \
        af[m] = *(const bf16x8*)&As[buf][(wm * 64 + m * 16 + lr) * 32 + ps]; \
    _Pragma("unroll") for (int n = 0; n < 4; ++n)                    \
        bf[n] = *(const bf16x8*)&Bs[buf][(wn * 64 + n * 16 + lr) * 32 + ps]; \
    __builtin_amdgcn_s_setprio(1);                                   \
    _Pragma("unroll") for (int m = 0; m < 4; ++m)                    \
        _Pragma("unroll") for (int n = 0; n < 4; ++n)                \
            acc[m][n] = __builtin_amdgcn_mfma_f32_16x16x32_bf16(     \
                af[m], bf[n], acc[m][n], 0, 0, 0);                   \
    __builtin_amdgcn_s_setprio(0);                                   \
  }

  STAGE(0, 0);
  STAGE(1, 1);
  for (int tt = 0; tt < 20; ++tt) {  // t = 0..59
    const int t = tt * 3;
    VM3; __builtin_amdgcn_s_barrier(); COMPUTE(0); STAGE(2, t + 2);
    VM3; __builtin_amdgcn_s_barrier(); COMPUTE(1); STAGE(0, t + 3);
    VM3; __builtin_amdgcn_s_barrier(); COMPUTE(2); STAGE(1, t + 4);
  }
  VM3; __builtin_amdgcn_s_barrier(); COMPUTE(0); STAGE(2, 62);  // t=60
  VM3; __builtin_amdgcn_s_barrier(); COMPUTE(1); STAGE(0, 63);  // t=61
  VM3; __builtin_amdgcn_s_barrier(); COMPUTE(2);                // t=62
  VM0; __builtin_amdgcn_s_barrier(); COMPUTE(0);                // t=63

  if (dense) {
    // inline exclusive prefix of cntA for this expert
    int base = 0;
#pragma unroll
    for (int j = 0; j < 16; ++j) base += (j < e) ? cntA[j] : 0;
    ushort_t* G = khalf ? g1 : g0;
#pragma unroll
    for (int m = 0; m < 4; ++m) {
#pragma unroll
      for (int i = 0; i < 4; ++i) {
        int gr = row0 + wm * 64 + m * 16 + (lane >> 4) * 4 + i;
        if (gr < cnt) {
#pragma unroll
          for (int n = 0; n < 4; ++n) {
            int o = o0 + wn * 64 + n * 16 + (lane & 15);
            G[(size_t)(base + gr) * O_ + o] = (ushort_t)bf16_rne(acc[m][n][i]);
          }
        }
      }
    }
  } else {  // fallback: atomic path (ws too small)
#pragma unroll
    for (int m = 0; m < 4; ++m) {
#pragma unroll
      for (int i = 0; i < 4; ++i) {
        int gr = row0 + wm * 64 + m * 16 + (lane >> 4) * 4 + i;
        if (gr < cnt) {
          int tk = tokL[e * B_ + gr];
          float wt = wgtL[e * B_ + gr];
#pragma unroll
          for (int n = 0; n < 4; ++n) {
            int o = o0 + wn * 64 + n * 16 + (lane & 15);
            float v = acc[m][n][i] + (khalf ? 0.f : be[e * O_ + o]);
            atomicAdd(&out[(size_t)tk * O_ + o], wt * v);
          }
        }
      }
    }
  }
#undef STAGE
#undef COMPUTE
}

// ---------------- kernel 2c: combine + fused balance loss ----------------
__global__ __launch_bounds__(256) void combine(
    const ushort_t* __restrict__ g0, const ushort_t* __restrict__ g1,
    const int* __restrict__ idxP, const float2* __restrict__ wP,
    const int* __restrict__ posA, const int* __restrict__ posB,
    const int* __restrict__ cntA, const float* __restrict__ be,
    const float* __restrict__ pblk, float* __restrict__ out) {
  const int tid = threadIdx.x;
  const int t = blockIdx.x * 4 + (tid >> 6);
  const int o = (tid & 63) * 8;
  const int pk = idxP[t];
  const int e0 = pk & 255, e1 = pk >> 8;
  const float2 wv = wP[t];
  int s = 0, off0 = 0, off1 = 0;
#pragma unroll
  for (int j = 0; j < 16; ++j) {
    if (j == e0) off0 = s;
    if (j == e1) off1 = s;
    s += cntA[j];
  }
  const size_t s0 = (size_t)(off0 + posA[t]) * O_ + o;
  const size_t s1 = (size_t)(off1 + posB[t]) * O_ + o;
  u16x8 a0 = *(const u16x8*)&g0[s0];
  u16x8 a1 = *(const u16x8*)&g1[s0];
  u16x8 b0 = *(const u16x8*)&g0[s1];
  u16x8 b1 = *(const u16x8*)&g1[s1];
  const float* be0 = &be[e0 * O_ + o];
  const float* be1 = &be[e1 * O_ + o];
  float r[8];
#pragma unroll
  for (int j = 0; j < 8; ++j) {
    float a = bf16_to_f32(a0[j]) + bf16_to_f32(a1[j]) + be0[j];
    float b = bf16_to_f32(b0[j]) + bf16_to_f32(b1[j]) + be1[j];
    r[j] = wv.x * a + wv.y * b;
  }
  *(f32x4*)&out[(size_t)t * O_ + o] = f32x4{r[0], r[1], r[2], r[3]};
  *(f32x4*)&out[(size_t)t * O_ + o + 4] = f32x4{r[4], r[5], r[6], r[7]};

  if (blockIdx.x == 0) {
    __shared__ float red[64];
    if (tid < 64) {
      const int e = tid & 15, g = tid >> 4;
      float acc = 0.f;
      for (int b = g; b < 512; b += 4) acc += pblk[b * 16 + e];
      red[tid] = acc;
    }
    __syncthreads();
    if (tid < 16) {
      float tot = (red[tid] + red[16 + tid]) + (red[32 + tid] + red[48 + tid]);
      float pi = tot * (1.f / (float)B_);
      red[tid] = pi * logf(fmaxf(pi, 1e-9f));
    }
    __syncthreads();
    if (tid == 0) {
      float loss = 0.f;
#pragma unroll
      for (int e2 = 0; e2 < 16; ++e2) loss += red[e2];
      out[(size_t)B_ * O_] = 0.01f * (loss + logf(16.f));
    }
  }
}

// ---------------- kernel 3: balance loss (fallback path only) ------------
__global__ __launch_bounds__(64) void finalize(const float* __restrict__ pblk,
                                               float* __restrict__ out) {
  __shared__ float red[64];
  const int tid = threadIdx.x;
  const int e = tid & 15, g = tid >> 4;
  float s = 0.f;
  for (int b = g; b < 512; b += 4) s += pblk[b * 16 + e];
  red[tid] = s;
  __syncthreads();
  if (tid < 16) {
    float tot = (red[tid] + red[16 + tid]) + (red[32 + tid] + red[48 + tid]);
    float pi = tot * (1.f / (float)B_);
    red[tid] = pi * logf(fmaxf(pi, 1e-9f));
  }
  __syncthreads();
  if (tid == 0) {
    float loss = 0.f;
#pragma unroll
    for (int e2 = 0; e2 < 16; ++e2) loss += red[e2];
    out[(size_t)B_ * O_] = 0.01f * (loss + logf(16.f));
  }
}

extern "C" void kernel_launch(void* const* d_in, const int* in_sizes, int n_in,
                              void* d_out, int out_size, void* d_ws,
                              size_t ws_size, hipStream_t stream) {
  const float* feat = (const float*)d_in[0];
  const float* Wr = (const float*)d_in[1];
  const float* br = (const float*)d_in[2];
  const float* We = (const float*)d_in[3];
  const float* be = (const float*)d_in[4];
  float* out = (float*)d_out;

  char* ws = (char*)d_ws;
  const size_t SZG     = (size_t)(2 * B_) * O_ * 2;   // 16 MiB per half (bf16)
  const size_t OFF_FEAT = 67108864;                   // 64 MiB Wbt
  const size_t OFF_G0   = OFF_FEAT + 67108864;        // 64 MiB featbf
  const size_t OFF_G1   = OFF_G0 + SZG;
  const size_t OFF_TOK  = OFF_G1 + SZG;
  const size_t OFF_WGT  = OFF_TOK + 524288;
  const size_t OFF_CNT  = OFF_WGT + 524288;
  const size_t OFF_IDX  = OFF_CNT + 256;
  const size_t OFF_WP   = OFF_IDX + 32768;
  const size_t OFF_PB   = OFF_WP + 65536;
  const size_t OFF_PA   = OFF_PB + 32768;
  const size_t OFF_PBo  = OFF_PA + 32768;
  const size_t OFF_WRT  = OFF_PBo + 32768;            // WrT: 256 KB
  const size_t NEED     = OFF_WRT + 262144;
  ushort_t* Wbt = (ushort_t*)ws;
  ushort_t* featbf = (ushort_t*)(ws + OFF_FEAT);
  ushort_t* g0 = (ushort_t*)(ws + OFF_G0);
  ushort_t* g1 = (ushort_t*)(ws + OFF_G1);
  int* tokL = (int*)(ws + OFF_TOK);
  float* wgtL = (float*)(ws + OFF_WGT);
  int* cntA = (int*)(ws + OFF_CNT);
  int* idxP = (int*)(ws + OFF_IDX);
  float2* wP = (float2*)(ws + OFF_WP);
  float* pblk = (float*)(ws + OFF_PB);
  int* posA = (int*)(ws + OFF_PA);
  int* posB = (int*)(ws + OFF_PBo);
  float* WrT = (float*)(ws + OFF_WRT);
  const int dense = ws_size >= NEED ? 1 : 0;

  if (!dense)
    hipMemsetAsync(out, 0, (size_t)(B_ * O_ + 1) * sizeof(float), stream);

  wr_transpose<<<D_ / 256, 256, 0, stream>>>(Wr, WrT);
  prep<<<512 + 2048, 256, 0, stream>>>(feat, WrT, br, We, featbf, Wbt, idxP,
                                       wP, pblk);
  bucket<<<E_, 256, 0, stream>>>(idxP, wP, tokL, wgtL, cntA, posA, posB);
  moe_gemm<<<4096, 512, 0, stream>>>(featbf, Wbt, be, tokL, wgtL, cntA, g0,
                                     g1, out, dense);
  if (dense)
    combine<<<B_ / 4, 256, 0, stream>>>(g0, g1, idxP, wP, posA, posB, cntA,
                                        be, pblk, out);
  else
    finalize<<<1, 64, 0, stream>>>(pblk, out);
}

// Round 16
// 251.300 us; speedup vs baseline: 1.2035x; 1.0280x over previous
//
#include <hip/hip_runtime.h>

// TopK MoE classifier: B=8192, D=4096, E=16, O=512, top-2.
//  k_wr: wr_transpose  W_r [D][E] -> WrT [E][D] f32 (NT reads)
//  k_prep: FUSED router_mlp + we_transpose (heterogeneous block ranges):
//      blocks 0..511: fp32 router logits/top-2 + feat f32->bf16 (featbf),
//      16 tokens/block; expert loop grouped x4 with hoisted WrT loads
//      (launch_bounds(256,2): R15's VGPR=80 starved load hoisting)
//      blocks 512..2559: W_e -> Wbt bf16 transpose, 4 tiles, dbuf prefetch
//      read-once streams (feat, We, Wr) use NON-TEMPORAL loads
//  k1b: bucket     16 blocks (1/expert), deterministic ballot compaction;
//       records posA/posB = token's slot inside its expert lists
//  k2: moe_gemm    grouped bf16 MFMA 128x256 (8 waves 2Mx4N), BK=32,
//      K-split=2, ring-3 LDS (72 KiB), counted vmcnt(3) + raw s_barrier,
//      XCD-contiguous work mapping; epilogue = plain CONTIGUOUS bf16
//      stores into g[cntOff[e]+row]
//  k2c: combine    out[t] = w0*(g0+g1+be[e0]) + w1*(g0+g1+be[e1]);
//       block 0 folds the balance-loss finalize

#define B_ 8192
#define D_ 4096
#define E_ 16
#define O_ 512

typedef unsigned int uint32;
typedef unsigned short ushort_t;
typedef __bf16 bf16_t;
typedef bf16_t bf16x8 __attribute__((ext_vector_type(8)));
typedef float f32x4 __attribute__((ext_vector_type(4)));
typedef ushort_t u16x8 __attribute__((ext_vector_type(8)));

__device__ __forceinline__ uint32 bf16_rne(float x) {
  uint32 u = __float_as_uint(x);
  return (u + 0x7fffu + ((u >> 16) & 1u)) >> 16;
}
__device__ __forceinline__ float bf16_to_f32(ushort_t u) {
  return __uint_as_float(((uint32)u) << 16);
}
__device__ __forceinline__ f32x4 ntload4(const float* p) {
  return __builtin_nontemporal_load((const f32x4*)p);
}

__device__ __forceinline__ void gload16(const void* g, void* l) {
  __builtin_amdgcn_global_load_lds(
      (const __attribute__((address_space(1))) void*)g,
      (__attribute__((address_space(3))) void*)l, 16, 0, 0);
}

// ---------------- kernel wr: W_r transpose ----------------
__global__ __launch_bounds__(256) void wr_transpose(
    const float* __restrict__ Wr, float* __restrict__ WrT) {
  const int d = blockIdx.x * 256 + threadIdx.x;
  const float* src = &Wr[(size_t)d * 16];
  f32x4 v0 = ntload4(src), v1 = ntload4(src + 4);
  f32x4 v2 = ntload4(src + 8), v3 = ntload4(src + 12);
  WrT[0 * D_ + d] = v0[0];  WrT[1 * D_ + d] = v0[1];
  WrT[2 * D_ + d] = v0[2];  WrT[3 * D_ + d] = v0[3];
  WrT[4 * D_ + d] = v1[0];  WrT[5 * D_ + d] = v1[1];
  WrT[6 * D_ + d] = v1[2];  WrT[7 * D_ + d] = v1[3];
  WrT[8 * D_ + d] = v2[0];  WrT[9 * D_ + d] = v2[1];
  WrT[10 * D_ + d] = v2[2]; WrT[11 * D_ + d] = v2[3];
  WrT[12 * D_ + d] = v3[0]; WrT[13 * D_ + d] = v3[1];
  WrT[14 * D_ + d] = v3[2]; WrT[15 * D_ + d] = v3[3];
}

// ---------------- fused prep: router (blocks 0..511) + We transpose -------
__global__ __launch_bounds__(256, 2) void prep(
    const float* __restrict__ feat, const float* __restrict__ WrT,
    const float* __restrict__ br, const float* __restrict__ We,
    ushort_t* __restrict__ featbf, ushort_t* __restrict__ Wbt,
    int* __restrict__ idxP, float2* __restrict__ wP,
    float* __restrict__ pblk) {
  __shared__ __align__(16) float shmem[64 * 65];  // union: router pw / we tile
  const int tid = threadIdx.x;

  if (blockIdx.x < 512) {
    // ---------------- router part ----------------
    const int lane = tid & 63, w = tid >> 6;
    const int tbase = blockIdx.x * 16 + w * 4;

    float acc[4][16] = {};

    for (int si = 0; si < 8; ++si) {
      const int d8 = si * 512 + lane * 8;
      f32x4 fa[4], fb[4];
#pragma unroll
      for (int i = 0; i < 4; ++i) {
        const float* fp = &feat[(size_t)(tbase + i) * D_ + d8];
        fa[i] = ntload4(fp);
        fb[i] = ntload4(fp + 4);
      }
#pragma unroll
      for (int i = 0; i < 4; ++i) {
        uint4 pk;
        pk.x = bf16_rne(fa[i][0]) | (bf16_rne(fa[i][1]) << 16);
        pk.y = bf16_rne(fa[i][2]) | (bf16_rne(fa[i][3]) << 16);
        pk.z = bf16_rne(fb[i][0]) | (bf16_rne(fb[i][1]) << 16);
        pk.w = bf16_rne(fb[i][2]) | (bf16_rne(fb[i][3]) << 16);
        *(uint4*)&featbf[(size_t)(tbase + i) * D_ + d8] = pk;
      }
      // expert loop grouped x4: issue all 8 WrT loads, then 128 FMAs.
      // FMA chain per (i,e) keeps d-ascending order -> bit-exact logits.
      const float* wb_ = &WrT[d8];
#pragma unroll
      for (int g = 0; g < 4; ++g) {
        f32x4 wa0 = *(const f32x4*)(wb_ + (size_t)(g * 4 + 0) * D_);
        f32x4 wq0 = *(const f32x4*)(wb_ + (size_t)(g * 4 + 0) * D_ + 4);
        f32x4 wa1 = *(const f32x4*)(wb_ + (size_t)(g * 4 + 1) * D_);
        f32x4 wq1 = *(const f32x4*)(wb_ + (size_t)(g * 4 + 1) * D_ + 4);
        f32x4 wa2 = *(const f32x4*)(wb_ + (size_t)(g * 4 + 2) * D_);
        f32x4 wq2 = *(const f32x4*)(wb_ + (size_t)(g * 4 + 2) * D_ + 4);
        f32x4 wa3 = *(const f32x4*)(wb_ + (size_t)(g * 4 + 3) * D_);
        f32x4 wq3 = *(const f32x4*)(wb_ + (size_t)(g * 4 + 3) * D_ + 4);
#pragma unroll
        for (int i = 0; i < 4; ++i) {
          float a0 = acc[i][g * 4 + 0], a1 = acc[i][g * 4 + 1];
          float a2 = acc[i][g * 4 + 2], a3 = acc[i][g * 4 + 3];
#pragma unroll
          for (int j = 0; j < 4; ++j) {
            a0 = fmaf(fa[i][j], wa0[j], a0);
            a1 = fmaf(fa[i][j], wa1[j], a1);
            a2 = fmaf(fa[i][j], wa2[j], a2);
            a3 = fmaf(fa[i][j], wa3[j], a3);
          }
#pragma unroll
          for (int j = 0; j < 4; ++j) {
            a0 = fmaf(fb[i][j], wq0[j], a0);
            a1 = fmaf(fb[i][j], wq1[j], a1);
            a2 = fmaf(fb[i][j], wq2[j], a2);
            a3 = fmaf(fb[i][j], wq3[j], a3);
          }
          acc[i][g * 4 + 0] = a0; acc[i][g * 4 + 1] = a1;
          acc[i][g * 4 + 2] = a2; acc[i][g * 4 + 3] = a3;
        }
      }
    }

    float psum[16];
#pragma unroll
    for (int e = 0; e < 16; ++e) psum[e] = 0.f;

#pragma unroll
    for (int i = 0; i < 4; ++i) {
      float l[16];
#pragma unroll
      for (int e = 0; e < 16; ++e) {
        float v = acc[i][e];
#pragma unroll
        for (int m = 32; m >= 1; m >>= 1) v += __shfl_xor(v, m, 64);
        l[e] = v + br[e];
      }
      float mx = l[0];
#pragma unroll
      for (int e = 1; e < 16; ++e) mx = fmaxf(mx, l[e]);
      float p[16];
      float s = 0.f;
#pragma unroll
      for (int e = 0; e < 16; ++e) { p[e] = expf(l[e] - mx); s += p[e]; }
      float inv = 1.f / s;
#pragma unroll
      for (int e = 0; e < 16; ++e) { p[e] *= inv; psum[e] += p[e]; }
      int i0 = 0; float v0 = p[0];
#pragma unroll
      for (int e = 1; e < 16; ++e) if (p[e] > v0) { v0 = p[e]; i0 = e; }
      int i1 = (i0 == 0) ? 1 : 0; float v1 = p[i1];
#pragma unroll
      for (int e = 0; e < 16; ++e)
        if (e != i0 && p[e] > v1) { v1 = p[e]; i1 = e; }
      float denom = fmaxf(v0 + v1, 1e-9f);
      if (lane == 0) {
        int t = tbase + i;
        idxP[t] = i0 | (i1 << 8);
        wP[t] = make_float2(v0 / denom, v1 / denom);
      }
    }
    if (lane == 0) {
#pragma unroll
      for (int e = 0; e < 16; ++e) shmem[w * 16 + e] = psum[e];
    }
    __syncthreads();
    if (tid < 16)
      pblk[blockIdx.x * 16 + tid] =
          (shmem[tid] + shmem[16 + tid]) + (shmem[32 + tid] + shmem[48 + tid]);
  } else {
    // ------- We transpose part: 4 tiles of 64x64, dbuf register prefetch --
    const int tx = tid & 15, ty = tid >> 4;
    const int wid = blockIdx.x - 512;  // 0..2047
    f32x4 cur[4], nxt[4];
    {
      const int tix = wid * 4;
      const int e = tix >> 9;
      const int rem = tix & 511;
      const int d0 = (rem >> 3) << 6, o0 = (rem & 7) << 6;
      const float* src = We + ((size_t)e * D_ + d0) * O_ + o0;
#pragma unroll
      for (int p = 0; p < 4; ++p)
        cur[p] = ntload4(src + (size_t)(ty + p * 16) * O_ + tx * 4);
    }
#pragma unroll
    for (int q = 0; q < 4; ++q) {
      const int tix = wid * 4 + q;
      const int e = tix >> 9;
      const int rem = tix & 511;
      const int d0 = (rem >> 3) << 6, o0 = (rem & 7) << 6;
      if (q) __syncthreads();
#pragma unroll
      for (int p = 0; p < 4; ++p) {
        int dl = ty + p * 16;
        shmem[dl * 65 + tx * 4 + 0] = cur[p][0];
        shmem[dl * 65 + tx * 4 + 1] = cur[p][1];
        shmem[dl * 65 + tx * 4 + 2] = cur[p][2];
        shmem[dl * 65 + tx * 4 + 3] = cur[p][3];
      }
      if (q < 3) {
        const int tix2 = tix + 1;
        const int e2 = tix2 >> 9;
        const int rem2 = tix2 & 511;
        const int d02 = (rem2 >> 3) << 6, o02 = (rem2 & 7) << 6;
        const float* src2 = We + ((size_t)e2 * D_ + d02) * O_ + o02;
#pragma unroll
        for (int p = 0; p < 4; ++p)
          nxt[p] = ntload4(src2 + (size_t)(ty + p * 16) * O_ + tx * 4);
      }
      __syncthreads();
      ushort_t* dst = Wbt + ((size_t)e * O_ + o0) * D_ + d0;
#pragma unroll
      for (int p = 0; p < 4; ++p) {
        int ol = ty + p * 16;
        uint2 pk;
        pk.x = bf16_rne(shmem[(tx * 4 + 0) * 65 + ol]) |
               (bf16_rne(shmem[(tx * 4 + 1) * 65 + ol]) << 16);
        pk.y = bf16_rne(shmem[(tx * 4 + 2) * 65 + ol]) |
               (bf16_rne(shmem[(tx * 4 + 3) * 65 + ol]) << 16);
        *(uint2*)(dst + (size_t)ol * D_ + tx * 4) = pk;
      }
#pragma unroll
      for (int p = 0; p < 4; ++p) cur[p] = nxt[p];
    }
  }
}

// ---------------- kernel 1b: deterministic expert bucketing ----------------
__global__ __launch_bounds__(256) void bucket(
    const int* __restrict__ idxP, const float2* __restrict__ wP,
    int* __restrict__ tokL, float* __restrict__ wgtL, int* __restrict__ cntA,
    int* __restrict__ posA, int* __restrict__ posB) {
  const int e = blockIdx.x;
  const int tid = threadIdx.x, lane = tid & 63, w = tid >> 6;
  __shared__ int wsum[4];
  __shared__ int basev;
  if (tid == 0) basev = 0;
  __syncthreads();

  for (int c = 0; c < B_; c += 256) {
    const int t = c + tid;
    const int pk = idxP[t];
    const float2 wv = wP[t];
    const bool m0 = (pk & 255) == e;
    const bool m1 = (pk >> 8) == e;
    const bool m = m0 || m1;
    const float wt = m0 ? wv.x : wv.y;
    unsigned long long bal = __ballot(m);
    int rank = __popcll(bal & ((1ull << lane) - 1ull));
    if (lane == 0) wsum[w] = __popcll(bal);
    __syncthreads();
    int wbase = basev;
    for (int q = 0; q < w; ++q) wbase += wsum[q];
    if (m) {
      int pos = wbase + rank;
      tokL[e * B_ + pos] = t;
      wgtL[e * B_ + pos] = wt;
      if (m0) posA[t] = pos; else posB[t] = pos;
    }
    __syncthreads();
    if (tid == 0) basev += (wsum[0] + wsum[1]) + (wsum[2] + wsum[3]);
  }
  __syncthreads();
  if (tid == 0) cntA[e] = basev;
}

// ---------------- kernel 2: grouped expert GEMM, 128x256, K-split=2 -------
// 8 waves (2Mx4N), BK=32, ring-3 LDS (72 KiB), counted vmcnt(3) + raw
// s_barrier (STAGE after COMPUTE). XCD-contiguous mapping. bf16 g epilogue,
// contiguous (cntOff[e]+row)-indexed stores.
#define VM3 asm volatile("s_waitcnt vmcnt(3)" ::: "memory")
#define VM0 asm volatile("s_waitcnt vmcnt(0)" ::: "memory")

__global__ __launch_bounds__(512, 4) void moe_gemm(
    const ushort_t* __restrict__ featbf, const ushort_t* __restrict__ Wbt,
    const float* __restrict__ be, const int* __restrict__ tokL,
    const float* __restrict__ wgtL, const int* __restrict__ cntA,
    ushort_t* __restrict__ g0, ushort_t* __restrict__ g1,
    float* __restrict__ out, int dense) {
  const int orig = blockIdx.x;                  // 0..4095
  const int work = (orig & 7) * 512 + (orig >> 3);
  const int z = work >> 7;                      // e*2 + khalf
  const int e = z >> 1, khalf = z & 1;
  const int cnt = cntA[e];
  const int row0 = ((work >> 1) & 63) * 128;
  if (row0 >= cnt) return;
  const int o0 = (work & 1) * 256;

  const int tid = threadIdx.x;
  const int lane = tid & 63, w = tid >> 6;      // w in [0,8)
  const int wm = w >> 2, wn = w & 3;            // 2M x 4N

  __shared__ __align__(16) ushort_t As[3][128 * 32];
  __shared__ __align__(16) ushort_t Bs[3][256 * 32];

  const int kg = (lane & 3) ^ ((lane >> 3) & 3);
  const size_t kbase = (size_t)khalf * 2048 + kg * 8;
  const int arow = row0 + w * 16 + (lane >> 2);
  const int atok = (arow < cnt) ? tokL[e * B_ + arow] : 0;
  const ushort_t* aS = featbf + (size_t)atok * D_ + kbase;
  const ushort_t* bS[2];
#pragma unroll
  for (int j = 0; j < 2; ++j) {
    int r = (2 * w + j) * 16 + (lane >> 2);
    bS[j] = Wbt + ((size_t)e * O_ + o0 + r) * D_ + kbase;
  }

  f32x4 acc[4][4] = {};
  const int lr = lane & 15;
  const int lg = lane >> 4;
  const int ps = (lg ^ ((lr >> 1) & 3)) * 8;

#define STAGE(buf, t)                                                \
  {                                                                  \
    gload16(aS + (t) * 32, &As[buf][(w * 16) * 32]);                 \
    gload16(bS[0] + (t) * 32, &Bs[buf][(2 * w) * 512]);              \
    gload16(bS[1] + (t) * 32, &Bs[buf][(2 * w + 1) * 512]);          \
  }

#define COMPUTE(buf)                                                 \
  {                                                                  \
    bf16x8 af[4], bf[4];                                             \
    _Pragma("unroll") for (int m = 0; m < 4; ++m)                    \
        af[m] = *(const bf16x8*)&As[buf][(wm * 64 + m * 16 + lr) * 32 + ps]; \
    _Pragma("unroll") for (int n = 0; n < 4; ++n)                    \
        bf[n] = *(const bf16x8*)&Bs[buf][(wn * 64 + n * 16 + lr) * 32 + ps]; \
    __builtin_amdgcn_s_setprio(1);                                   \
    _Pragma("unroll") for (int m = 0; m < 4; ++m)                    \
        _Pragma("unroll") for (int n = 0; n < 4; ++n)                \
            acc[m][n] = __builtin_amdgcn_mfma_f32_16x16x32_bf16(     \
                af[m], bf[n], acc[m][n], 0, 0, 0);                   \
    __builtin_amdgcn_s_setprio(0);                                   \
  }

  STAGE(0, 0);
  STAGE(1, 1);
  for (int tt = 0; tt < 20; ++tt) {  // t = 0..59
    const int t = tt * 3;
    VM3; __builtin_amdgcn_s_barrier(); COMPUTE(0); STAGE(2, t + 2);
    VM3; __builtin_amdgcn_s_barrier(); COMPUTE(1); STAGE(0, t + 3);
    VM3; __builtin_amdgcn_s_barrier(); COMPUTE(2); STAGE(1, t + 4);
  }
  VM3; __builtin_amdgcn_s_barrier(); COMPUTE(0); STAGE(2, 62);  // t=60
  VM3; __builtin_amdgcn_s_barrier(); COMPUTE(1); STAGE(0, 63);  // t=61
  VM3; __builtin_amdgcn_s_barrier(); COMPUTE(2);                // t=62
  VM0; __builtin_amdgcn_s_barrier(); COMPUTE(0);                // t=63

  if (dense) {
    // inline exclusive prefix of cntA for this expert
    int base = 0;
#pragma unroll
    for (int j = 0; j < 16; ++j) base += (j < e) ? cntA[j] : 0;
    ushort_t* G = khalf ? g1 : g0;
#pragma unroll
    for (int m = 0; m < 4; ++m) {
#pragma unroll
      for (int i = 0; i < 4; ++i) {
        int gr = row0 + wm * 64 + m * 16 + (lane >> 4) * 4 + i;
        if (gr < cnt) {
#pragma unroll
          for (int n = 0; n < 4; ++n) {
            int o = o0 + wn * 64 + n * 16 + (lane & 15);
            G[(size_t)(base + gr) * O_ + o] = (ushort_t)bf16_rne(acc[m][n][i]);
          }
        }
      }
    }
  } else {  // fallback: atomic path (ws too small)
#pragma unroll
    for (int m = 0; m < 4; ++m) {
#pragma unroll
      for (int i = 0; i < 4; ++i) {
        int gr = row0 + wm * 64 + m * 16 + (lane >> 4) * 4 + i;
        if (gr < cnt) {
          int tk = tokL[e * B_ + gr];
          float wt = wgtL[e * B_ + gr];
#pragma unroll
          for (int n = 0; n < 4; ++n) {
            int o = o0 + wn * 64 + n * 16 + (lane & 15);
            float v = acc[m][n][i] + (khalf ? 0.f : be[e * O_ + o]);
            atomicAdd(&out[(size_t)tk * O_ + o], wt * v);
          }
        }
      }
    }
  }
#undef STAGE
#undef COMPUTE
}

// ---------------- kernel 2c: combine + fused balance loss ----------------
__global__ __launch_bounds__(256) void combine(
    const ushort_t* __restrict__ g0, const ushort_t* __restrict__ g1,
    const int* __restrict__ idxP, const float2* __restrict__ wP,
    const int* __restrict__ posA, const int* __restrict__ posB,
    const int* __restrict__ cntA, const float* __restrict__ be,
    const float* __restrict__ pblk, float* __restrict__ out) {
  const int tid = threadIdx.x;
  const int t = blockIdx.x * 4 + (tid >> 6);
  const int o = (tid & 63) * 8;
  const int pk = idxP[t];
  const int e0 = pk & 255, e1 = pk >> 8;
  const float2 wv = wP[t];
  int s = 0, off0 = 0, off1 = 0;
#pragma unroll
  for (int j = 0; j < 16; ++j) {
    if (j == e0) off0 = s;
    if (j == e1) off1 = s;
    s += cntA[j];
  }
  const size_t s0 = (size_t)(off0 + posA[t]) * O_ + o;
  const size_t s1 = (size_t)(off1 + posB[t]) * O_ + o;
  u16x8 a0 = *(const u16x8*)&g0[s0];
  u16x8 a1 = *(const u16x8*)&g1[s0];
  u16x8 b0 = *(const u16x8*)&g0[s1];
  u16x8 b1 = *(const u16x8*)&g1[s1];
  const float* be0 = &be[e0 * O_ + o];
  const float* be1 = &be[e1 * O_ + o];
  float r[8];
#pragma unroll
  for (int j = 0; j < 8; ++j) {
    float a = bf16_to_f32(a0[j]) + bf16_to_f32(a1[j]) + be0[j];
    float b = bf16_to_f32(b0[j]) + bf16_to_f32(b1[j]) + be1[j];
    r[j] = wv.x * a + wv.y * b;
  }
  *(f32x4*)&out[(size_t)t * O_ + o] = f32x4{r[0], r[1], r[2], r[3]};
  *(f32x4*)&out[(size_t)t * O_ + o + 4] = f32x4{r[4], r[5], r[6], r[7]};

  if (blockIdx.x == 0) {
    __shared__ float red[64];
    if (tid < 64) {
      const int e = tid & 15, g = tid >> 4;
      float acc = 0.f;
      for (int b = g; b < 512; b += 4) acc += pblk[b * 16 + e];
      red[tid] = acc;
    }
    __syncthreads();
    if (tid < 16) {
      float tot = (red[tid] + red[16 + tid]) + (red[32 + tid] + red[48 + tid]);
      float pi = tot * (1.f / (float)B_);
      red[tid] = pi * logf(fmaxf(pi, 1e-9f));
    }
    __syncthreads();
    if (tid == 0) {
      float loss = 0.f;
#pragma unroll
      for (int e2 = 0; e2 < 16; ++e2) loss += red[e2];
      out[(size_t)B_ * O_] = 0.01f * (loss + logf(16.f));
    }
  }
}

// ---------------- kernel 3: balance loss (fallback path only) ------------
__global__ __launch_bounds__(64) void finalize(const float* __restrict__ pblk,
                                               float* __restrict__ out) {
  __shared__ float red[64];
  const int tid = threadIdx.x;
  const int e = tid & 15, g = tid >> 4;
  float s = 0.f;
  for (int b = g; b < 512; b += 4) s += pblk[b * 16 + e];
  red[tid] = s;
  __syncthreads();
  if (tid < 16) {
    float tot = (red[tid] + red[16 + tid]) + (red[32 + tid] + red[48 + tid]);
    float pi = tot * (1.f / (float)B_);
    red[tid] = pi * logf(fmaxf(pi, 1e-9f));
  }
  __syncthreads();
  if (tid == 0) {
    float loss = 0.f;
#pragma unroll
    for (int e2 = 0; e2 < 16; ++e2) loss += red[e2];
    out[(size_t)B_ * O_] = 0.01f * (loss + logf(16.f));
  }
}

extern "C" void kernel_launch(void* const* d_in, const int* in_sizes, int n_in,
                              void* d_out, int out_size, void* d_ws,
                              size_t ws_size, hipStream_t stream) {
  const float* feat = (const float*)d_in[0];
  const float* Wr = (const float*)d_in[1];
  const float* br = (const float*)d_in[2];
  const float* We = (const float*)d_in[3];
  const float* be = (const float*)d_in[4];
  float* out = (float*)d_out;

  char* ws = (char*)d_ws;
  const size_t SZG     = (size_t)(2 * B_) * O_ * 2;   // 16 MiB per half (bf16)
  const size_t OFF_FEAT = 67108864;                   // 64 MiB Wbt
  const size_t OFF_G0   = OFF_FEAT + 67108864;        // 64 MiB featbf
  const size_t OFF_G1   = OFF_G0 + SZG;
  const size_t OFF_TOK  = OFF_G1 + SZG;
  const size_t OFF_WGT  = OFF_TOK + 524288;
  const size_t OFF_CNT  = OFF_WGT + 524288;
  const size_t OFF_IDX  = OFF_CNT + 256;
  const size_t OFF_WP   = OFF_IDX + 32768;
  const size_t OFF_PB   = OFF_WP + 65536;
  const size_t OFF_PA   = OFF_PB + 32768;
  const size_t OFF_PBo  = OFF_PA + 32768;
  const size_t OFF_WRT  = OFF_PBo + 32768;            // WrT: 256 KB
  const size_t NEED     = OFF_WRT + 262144;
  ushort_t* Wbt = (ushort_t*)ws;
  ushort_t* featbf = (ushort_t*)(ws + OFF_FEAT);
  ushort_t* g0 = (ushort_t*)(ws + OFF_G0);
  ushort_t* g1 = (ushort_t*)(ws + OFF_G1);
  int* tokL = (int*)(ws + OFF_TOK);
  float* wgtL = (float*)(ws + OFF_WGT);
  int* cntA = (int*)(ws + OFF_CNT);
  int* idxP = (int*)(ws + OFF_IDX);
  float2* wP = (float2*)(ws + OFF_WP);
  float* pblk = (float*)(ws + OFF_PB);
  int* posA = (int*)(ws + OFF_PA);
  int* posB = (int*)(ws + OFF_PBo);
  float* WrT = (float*)(ws + OFF_WRT);
  const int dense = ws_size >= NEED ? 1 : 0;

  if (!dense)
    hipMemsetAsync(out, 0, (size_t)(B_ * O_ + 1) * sizeof(float), stream);

  wr_transpose<<<D_ / 256, 256, 0, stream>>>(Wr, WrT);
  prep<<<512 + 2048, 256, 0, stream>>>(feat, WrT, br, We, featbf, Wbt, idxP,
                                       wP, pblk);
  bucket<<<E_, 256, 0, stream>>>(idxP, wP, tokL, wgtL, cntA, posA, posB);
  moe_gemm<<<4096, 512, 0, stream>>>(featbf, Wbt, be, tokL, wgtL, cntA, g0,
                                     g1, out, dense);
  if (dense)
    combine<<<B_ / 4, 256, 0, stream>>>(g0, g1, idxP, wP, posA, posB, cntA,
                                        be, pblk, out);
  else
    finalize<<<1, 64, 0, stream>>>(pblk, out);
}